// Round 6
// baseline (580.314 us; speedup 1.0000x reference)
//
#include <hip/hip_runtime.h>

typedef _Float16 f16x8 __attribute__((ext_vector_type(8)));
typedef unsigned short u16x4 __attribute__((ext_vector_type(4)));
typedef float f32x4 __attribute__((ext_vector_type(4)));

#define VMWAIT(N) asm volatile("s_waitcnt vmcnt(" #N ")" ::: "memory")
#define LGKM0()   asm volatile("s_waitcnt lgkmcnt(0)" ::: "memory")
#define RBAR()    do { asm volatile("" ::: "memory"); __builtin_amdgcn_s_barrier(); \
                       asm volatile("" ::: "memory"); } while (0)

__device__ __forceinline__ u16x4 cvt4(float4 v) {
    u16x4 h;
    h[0] = __builtin_bit_cast(unsigned short, (_Float16)v.x);
    h[1] = __builtin_bit_cast(unsigned short, (_Float16)v.y);
    h[2] = __builtin_bit_cast(unsigned short, (_Float16)v.z);
    h[3] = __builtin_bit_cast(unsigned short, (_Float16)v.w);
    return h;
}

// ---------------------------------------------------------------------------
// Kernel 0: W [K,U] f32 -> fp16 image, layout [ktile=k>>5][u][k&31] u16.
// ---------------------------------------------------------------------------
__global__ void convert_w_kernel(const float* __restrict__ w1,
                                 const float* __restrict__ w2,
                                 unsigned short* __restrict__ w1img,
                                 unsigned short* __restrict__ w2img) {
    int u = blockIdx.x;                           // 0..511
    int k = threadIdx.x + blockIdx.y * 256;       // 0..511
    size_t idx = (size_t)(k >> 5) * 16384 + (size_t)u * 32 + (k & 31);
    _Float16 h1 = (_Float16)w1[(size_t)k * 512 + u];
    _Float16 h2 = (_Float16)w2[(size_t)k * 512 + u];
    w1img[idx] = __builtin_bit_cast(unsigned short, h1);
    w2img[idx] = __builtin_bit_cast(unsigned short, h2);
}

// ---------------------------------------------------------------------------
// (h2 kernel helpers, unchanged round-5 structure)
// ---------------------------------------------------------------------------
__device__ __forceinline__ void stage_a64(const float* __restrict__ src,
                                          char* As, int tid) {
    const int row = tid >> 2, q = tid & 3;
    const float* p = src + (size_t)row * 512 + q * 4;
    const int sw2 = ((row >> 1) & 3) << 4;
    char* wb = As + row * 64;
    float4 va[4], vb[4];
#define AISS(V, G) { _Pragma("unroll") \
    for (int j_ = 0; j_ < 4; ++j_) V[j_] = *(const float4*)(p + ((G) * 4 + j_) * 16); }
#define APRC(V, G) { _Pragma("unroll") \
    for (int j_ = 0; j_ < 4; ++j_) { \
        const int i_ = (G) * 4 + j_; \
        *(u16x4*)(wb + (i_ >> 1) * 4096 + ((q * 8 + (i_ & 1) * 32) ^ sw2)) = cvt4(V[j_]); } }
    AISS(va, 0); AISS(vb, 1);
    VMWAIT(4); APRC(va, 0); AISS(va, 2);
    VMWAIT(4); APRC(vb, 1); AISS(vb, 3);
    VMWAIT(4); APRC(va, 2); AISS(va, 4);
    VMWAIT(4); APRC(vb, 3); AISS(vb, 5);
    VMWAIT(4); APRC(va, 4); AISS(va, 6);
    VMWAIT(4); APRC(vb, 5); AISS(vb, 7);
    VMWAIT(4); APRC(va, 6);
    VMWAIT(0); APRC(vb, 7);
#undef AISS
#undef APRC
}

__device__ __forceinline__ void chunk_gemm(const char* __restrict__ bcol,
                                           const char* As, const int* aoff,
                                           f32x4 acc[4][4]) {
    f16x8 brA[4], brB[4], afA[4], afB[4];
    #pragma unroll
    for (int i = 0; i < 4; ++i)
        #pragma unroll
        for (int j = 0; j < 4; ++j) acc[i][j] = (f32x4){0.f, 0.f, 0.f, 0.f};
    #pragma unroll
    for (int j = 0; j < 4; ++j) brA[j] = *(const f16x8*)(bcol + j * 1024);
    #pragma unroll
    for (int j = 0; j < 4; ++j) brB[j] = *(const f16x8*)(bcol + 32768 + j * 1024);
    #pragma unroll
    for (int i = 0; i < 4; ++i) afA[i] = *(const f16x8*)(As + aoff[i]);
    #pragma unroll
    for (int tt = 0; tt < 8; ++tt) {
        const int t0 = 2 * tt, t1 = t0 + 1;
        #pragma unroll
        for (int i = 0; i < 4; ++i)
            afB[i] = *(const f16x8*)(As + t1 * 4096 + aoff[i]);
        VMWAIT(4);
        #pragma unroll
        for (int i = 0; i < 4; ++i)
            #pragma unroll
            for (int j = 0; j < 4; ++j)
                acc[i][j] = __builtin_amdgcn_mfma_f32_16x16x32_f16(afA[i], brA[j], acc[i][j], 0, 0, 0);
        if (t0 < 14) {
            #pragma unroll
            for (int j = 0; j < 4; ++j)
                brA[j] = *(const f16x8*)(bcol + (t0 + 2) * 32768 + j * 1024);
        }
        if (t1 < 15) {
            #pragma unroll
            for (int i = 0; i < 4; ++i)
                afA[i] = *(const f16x8*)(As + (t1 + 1) * 4096 + aoff[i]);
        }
        if (t1 < 14) { VMWAIT(4); } else { VMWAIT(0); }
        #pragma unroll
        for (int i = 0; i < 4; ++i)
            #pragma unroll
            for (int j = 0; j < 4; ++j)
                acc[i][j] = __builtin_amdgcn_mfma_f32_16x16x32_f16(afB[i], brB[j], acc[i][j], 0, 0, 0);
        if (t1 < 14) {
            #pragma unroll
            for (int j = 0; j < 4; ++j)
                brB[j] = *(const f16x8*)(bcol + (t1 + 2) * 32768 + j * 1024);
        }
    }
}

__global__ __launch_bounds__(256, 2)
void h2_gemm_kernel(const float* __restrict__ hidden,
                    const char* __restrict__ w2img,
                    const float* __restrict__ b2,
                    float* __restrict__ h2o) {
    __shared__ char As[65536];
    const int tid = threadIdx.x, bm = blockIdx.x;
    const int lane = tid & 63, wid = tid >> 6;
    const int lane16 = lane & 15, g = lane >> 4;
    stage_a64(hidden + (size_t)bm * 32768, As, tid);
    __syncthreads();
    int aoff[4];
    #pragma unroll
    for (int i = 0; i < 4; ++i)
        aoff[i] = (i * 16 + lane16) * 64 + ((g ^ ((lane16 >> 1) & 3)) << 4);
    #pragma unroll
    for (int c = 0; c < 2; ++c) {
        const char* bcol = w2img + (size_t)(wid * 128 + c * 64 + lane16) * 64 + g * 16;
        f32x4 acc[4][4];
        chunk_gemm(bcol, As, aoff, acc);
        #pragma unroll
        for (int j = 0; j < 4; ++j) {
            int col = wid * 128 + c * 64 + j * 16 + lane16;
            float bb = b2[col];
            #pragma unroll
            for (int i = 0; i < 4; ++i)
                #pragma unroll
                for (int r = 0; r < 4; ++r)
                    h2o[(size_t)(bm * 64 + i * 16 + g * 4 + r) * 512 + col] = acc[i][j][r] + bb;
        }
    }
}

// ---------------------------------------------------------------------------
// Consumer-wave 64x128 chunk GEMM (K=512, 16 steps). A from LDS (dbuf'd
// ds_read_b128), B global->reg from L2-hot image, 2-deep prefetch.
// Pure-B vmcnt FIFO: one VMWAIT(8) per step.
// ---------------------------------------------------------------------------
__device__ __forceinline__ void chunk128(const char* __restrict__ bcol,
                                         const char* As, const int* aoff,
                                         f32x4 acc[4][8]) {
    f16x8 brA[8], brB[8], afA[4], afB[4];
    #pragma unroll
    for (int i = 0; i < 4; ++i)
        #pragma unroll
        for (int j = 0; j < 8; ++j) acc[i][j] = (f32x4){0.f, 0.f, 0.f, 0.f};
    #pragma unroll
    for (int j = 0; j < 8; ++j) brA[j] = *(const f16x8*)(bcol + j * 1024);
    #pragma unroll
    for (int j = 0; j < 8; ++j) brB[j] = *(const f16x8*)(bcol + 32768 + j * 1024);
    #pragma unroll
    for (int i = 0; i < 4; ++i) afA[i] = *(const f16x8*)(As + aoff[i]);
    #pragma unroll
    for (int tt = 0; tt < 8; ++tt) {
        const int t0 = 2 * tt, t1 = t0 + 1;
        #pragma unroll
        for (int i = 0; i < 4; ++i)
            afB[i] = *(const f16x8*)(As + t1 * 4096 + aoff[i]);
        VMWAIT(8);
        __builtin_amdgcn_s_setprio(1);
        #pragma unroll
        for (int i = 0; i < 4; ++i)
            #pragma unroll
            for (int j = 0; j < 8; ++j)
                acc[i][j] = __builtin_amdgcn_mfma_f32_16x16x32_f16(afA[i], brA[j], acc[i][j], 0, 0, 0);
        __builtin_amdgcn_s_setprio(0);
        if (t0 < 14) {
            #pragma unroll
            for (int j = 0; j < 8; ++j)
                brA[j] = *(const f16x8*)(bcol + (t0 + 2) * 32768 + j * 1024);
        }
        if (t1 < 15) {
            #pragma unroll
            for (int i = 0; i < 4; ++i)
                afA[i] = *(const f16x8*)(As + (t1 + 1) * 4096 + aoff[i]);
        }
        if (t1 < 14) { VMWAIT(8); } else { VMWAIT(0); }
        __builtin_amdgcn_s_setprio(1);
        #pragma unroll
        for (int i = 0; i < 4; ++i)
            #pragma unroll
            for (int j = 0; j < 8; ++j)
                acc[i][j] = __builtin_amdgcn_mfma_f32_16x16x32_f16(afB[i], brB[j], acc[i][j], 0, 0, 0);
        __builtin_amdgcn_s_setprio(0);
        if (t1 < 14) {
            #pragma unroll
            for (int j = 0; j < 8; ++j)
                brB[j] = *(const f16x8*)(bcol + (t1 + 2) * 32768 + j * 1024);
        }
    }
}

// ---------------------------------------------------------------------------
// Kernel B (fused, producer/consumer): 512 thr = 4 consumer + 4 producer
// waves. Block handles 4 batches; A dbuf 2x64KB; raw barriers only so
// producer HBM loads stay in flight across them. Per batch:
//   consumers: chunk128 -> tanh·Wv scores -> spl       producers: issue grp0
//   [#1]  softmax(tid<64)  [#2]
//   consumers: context from As[cur] -> out             producers: write grp0,
//   [#3]                                                issue+write grp1
// ---------------------------------------------------------------------------
__global__ __launch_bounds__(512, 2)
void fused_all_kernel(const float* __restrict__ feat,
                      const char* __restrict__ w1img,
                      const float* __restrict__ h2,
                      const float* __restrict__ b1,
                      const float* __restrict__ wv,
                      float* __restrict__ out) {
    __shared__ char As[2][65536];
    __shared__ float spl[256];
    __shared__ float wsm[64];

    const int tid = threadIdx.x;
    const int b0 = blockIdx.x * 4;
    const bool consumer = (tid < 256);
    const int lane16 = tid & 15, g = (tid >> 4) & 3;
    const int wid = tid >> 6;                 // consumer: 0..3

    // ---- prologue: ALL 512 threads stage batch b0 -> As[0] ----
    {
        const int row = tid >> 3, q = tid & 7;
        const float* p = feat + (size_t)b0 * 32768 + (size_t)row * 512 + q * 4;
        char* wb = As[0] + row * 64 + ((q * 8) ^ (((row >> 1) & 3) << 4));
        float4 v[16];
        #pragma unroll
        for (int i = 0; i < 16; ++i) v[i] = *(const float4*)(p + i * 32);
        VMWAIT(12);
        #pragma unroll
        for (int i = 0; i < 4; ++i)   *(u16x4*)(wb + i * 4096) = cvt4(v[i]);
        VMWAIT(8);
        #pragma unroll
        for (int i = 4; i < 8; ++i)   *(u16x4*)(wb + i * 4096) = cvt4(v[i]);
        VMWAIT(4);
        #pragma unroll
        for (int i = 8; i < 12; ++i)  *(u16x4*)(wb + i * 4096) = cvt4(v[i]);
        VMWAIT(0);
        #pragma unroll
        for (int i = 12; i < 16; ++i) *(u16x4*)(wb + i * 4096) = cvt4(v[i]);
    }
    LGKM0();
    RBAR();

    int aoff[4];
    #pragma unroll
    for (int i = 0; i < 4; ++i)
        aoff[i] = (i * 16 + lane16) * 64 + ((g ^ ((lane16 >> 1) & 3)) << 4);
    const char* bcol = w1img + (size_t)(wid * 128 + lane16) * 64 + g * 16;

    const int prow = (tid & 255) >> 2, pq = tid & 3;   // producer coords
    const int psw2 = ((prow >> 1) & 3) << 4;

    #pragma unroll 1
    for (int it = 0; it < 4; ++it) {
        const int cur = it & 1;
        const int b = b0 + it;
        float4 pv[16];
        if (consumer) {
            f32x4 acc[4][8];
            chunk128(bcol, As[cur], aoff, acc);
            float hhv[8], wvv[8];          // FIFO clean after chunk's VMWAIT(0)
            #pragma unroll
            for (int j = 0; j < 8; ++j) {
                int u = wid * 128 + j * 16 + lane16;
                hhv[j] = b1[u] + h2[(size_t)b * 512 + u];
                wvv[j] = wv[u];
            }
            #pragma unroll
            for (int i = 0; i < 4; ++i) {
                #pragma unroll
                for (int r = 0; r < 4; ++r) {
                    float s = 0.f;
                    #pragma unroll
                    for (int j = 0; j < 8; ++j) {
                        float h = acc[i][j][r] + hhv[j];
                        float ex = __expf(2.f * h);
                        s += (1.f - 2.f * __builtin_amdgcn_rcpf(ex + 1.f)) * wvv[j];
                    }
                    s += __shfl_xor(s, 1); s += __shfl_xor(s, 2);
                    s += __shfl_xor(s, 4); s += __shfl_xor(s, 8);
                    if (lane16 == 0) spl[(i * 16 + g * 4 + r) * 4 + wid] = s;
                }
            }
            LGKM0();
        } else if (it < 3) {
            // producers: issue first half of batch b+1 (16 HBM loads; stay
            // in flight across the raw barriers below)
            const float* p = feat + (size_t)(b + 1) * 32768 + (size_t)prow * 512 + pq * 4;
            #pragma unroll
            for (int i = 0; i < 16; ++i) pv[i] = *(const float4*)(p + i * 16);
        }
        RBAR();   // #1: scores ready
        if (tid < 64) {
            float s = (spl[tid * 4 + 0] + spl[tid * 4 + 1]) +
                      (spl[tid * 4 + 2] + spl[tid * 4 + 3]);
            float m = s;
            #pragma unroll
            for (int off = 32; off; off >>= 1) m = fmaxf(m, __shfl_xor(m, off));
            float e = __expf(s - m);
            float sum = e;
            #pragma unroll
            for (int off = 32; off; off >>= 1) sum += __shfl_xor(sum, off);
            wsm[tid] = e / sum;
            LGKM0();
        }
        RBAR();   // #2: wsm ready
        if (consumer) {
            // context from LDS fp16 A: thread owns cols {2*tid, 2*tid+1}
            const int cseg = (tid >> 4) * 4096;
            const int cin = (tid & 15) * 4;
            float ax = 0.f, ay = 0.f;
            #pragma unroll 8
            for (int s = 0; s < 64; ++s) {
                unsigned vv = *(const unsigned*)(As[cur] + cseg + s * 64 +
                                                (cin ^ (((s >> 1) & 3) << 4)));
                float w = wsm[s];
                ax += w * (float)__builtin_bit_cast(_Float16, (unsigned short)(vv & 0xffffu));
                ay += w * (float)__builtin_bit_cast(_Float16, (unsigned short)(vv >> 16));
            }
            ((float2*)out)[(size_t)b * 256 + tid] = make_float2(ax, ay);
        } else if (it < 3) {
            // producers: write grp0, issue+write grp1 (runs parallel to context)
            char* wb = As[cur ^ 1] + prow * 64;
            VMWAIT(0);
            #pragma unroll
            for (int i = 0; i < 16; ++i)
                *(u16x4*)(wb + (i >> 1) * 4096 + (((i & 1) * 32 + pq * 8) ^ psw2)) = cvt4(pv[i]);
            const float* p = feat + (size_t)(b + 1) * 32768 + (size_t)prow * 512 + pq * 4 + 256;
            #pragma unroll
            for (int i = 0; i < 16; ++i) pv[i] = *(const float4*)(p + i * 16);
            VMWAIT(0);
            #pragma unroll
            for (int i = 0; i < 16; ++i)
                *(u16x4*)(wb + ((i + 16) >> 1) * 4096 + (((i & 1) * 32 + pq * 8) ^ psw2)) = cvt4(pv[i]);
            LGKM0();
        }
        RBAR();   // #3: As[cur^1] staged, context done
    }
}

// ---------------------------------------------------------------------------
extern "C" void kernel_launch(void* const* d_in, const int* in_sizes, int n_in,
                              void* d_out, int out_size, void* d_ws, size_t ws_size,
                              hipStream_t stream) {
    (void)in_sizes; (void)n_in; (void)out_size; (void)ws_size;
    const float* feat   = (const float*)d_in[0];   // [2048,64,512]
    const float* hidden = (const float*)d_in[1];   // [2048,512]
    const float* W1     = (const float*)d_in[2];   // [512,512]
    const float* b1     = (const float*)d_in[3];   // [512]
    const float* W2     = (const float*)d_in[4];   // [512,512]
    const float* b2     = (const float*)d_in[5];   // [512]
    const float* Wv     = (const float*)d_in[6];   // [512,1]
    // d_in[7] = bv: softmax shift-invariant, unused.
    float* out = (float*)d_out;                    // [2048,512]

    char* ws = (char*)d_ws;
    unsigned short* w1img = (unsigned short*)(ws);            // 512 KB
    unsigned short* w2img = (unsigned short*)(ws + 524288);   // 512 KB
    float* h2 = (float*)(ws + 1048576);                       // 4 MB

    convert_w_kernel<<<dim3(512, 2), dim3(256), 0, stream>>>(W1, W2, w1img, w2img);
    h2_gemm_kernel<<<dim3(32), dim3(256), 0, stream>>>(hidden, (const char*)w2img, b2, h2);
    fused_all_kernel<<<dim3(512), dim3(512), 0, stream>>>(feat, (const char*)w1img, h2, b1, Wv, out);
}

// Round 7
// 273.371 us; speedup vs baseline: 2.1228x; 2.1228x over previous
//
#include <hip/hip_runtime.h>

typedef _Float16 f16x8 __attribute__((ext_vector_type(8)));
typedef unsigned short u16x4 __attribute__((ext_vector_type(4)));
typedef float f32x4 __attribute__((ext_vector_type(4)));

#define VMWAIT(N) asm volatile("s_waitcnt vmcnt(" #N ")" ::: "memory")
#define LGKM0()   asm volatile("s_waitcnt lgkmcnt(0)" ::: "memory")
#define FENCE()   asm volatile("" ::: "memory")
#define RBAR()    do { FENCE(); __builtin_amdgcn_s_barrier(); FENCE(); } while (0)

__device__ __forceinline__ u16x4 cvt4(float4 v) {
    u16x4 h;
    h[0] = __builtin_bit_cast(unsigned short, (_Float16)v.x);
    h[1] = __builtin_bit_cast(unsigned short, (_Float16)v.y);
    h[2] = __builtin_bit_cast(unsigned short, (_Float16)v.z);
    h[3] = __builtin_bit_cast(unsigned short, (_Float16)v.w);
    return h;
}

// ---------------------------------------------------------------------------
// Kernel 0: W [K,U] f32 -> fp16 image, layout [ktile=k>>5][u][k&31] u16.
// ---------------------------------------------------------------------------
__global__ void convert_w_kernel(const float* __restrict__ w1,
                                 const float* __restrict__ w2,
                                 unsigned short* __restrict__ w1img,
                                 unsigned short* __restrict__ w2img) {
    int u = blockIdx.x;
    int k = threadIdx.x + blockIdx.y * 256;
    size_t idx = (size_t)(k >> 5) * 16384 + (size_t)u * 32 + (k & 31);
    _Float16 h1 = (_Float16)w1[(size_t)k * 512 + u];
    _Float16 h2 = (_Float16)w2[(size_t)k * 512 + u];
    w1img[idx] = __builtin_bit_cast(unsigned short, h1);
    w2img[idx] = __builtin_bit_cast(unsigned short, h2);
}

// ---------------------------------------------------------------------------
// h2 kernel (round-5 structure, verbatim; proven correct/fast enough)
// ---------------------------------------------------------------------------
__device__ __forceinline__ void stage_a64(const float* __restrict__ src,
                                          char* As, int tid) {
    const int row = tid >> 2, q = tid & 3;
    const float* p = src + (size_t)row * 512 + q * 4;
    const int sw2 = ((row >> 1) & 3) << 4;
    char* wb = As + row * 64;
    float4 va[4], vb[4];
#define AISS(V, G) { _Pragma("unroll") \
    for (int j_ = 0; j_ < 4; ++j_) V[j_] = *(const float4*)(p + ((G) * 4 + j_) * 16); }
#define APRC(V, G) { _Pragma("unroll") \
    for (int j_ = 0; j_ < 4; ++j_) { \
        const int i_ = (G) * 4 + j_; \
        *(u16x4*)(wb + (i_ >> 1) * 4096 + ((q * 8 + (i_ & 1) * 32) ^ sw2)) = cvt4(V[j_]); } }
    AISS(va, 0); AISS(vb, 1);
    VMWAIT(4); APRC(va, 0); AISS(va, 2);
    VMWAIT(4); APRC(vb, 1); AISS(vb, 3);
    VMWAIT(4); APRC(va, 2); AISS(va, 4);
    VMWAIT(4); APRC(vb, 3); AISS(vb, 5);
    VMWAIT(4); APRC(va, 4); AISS(va, 6);
    VMWAIT(4); APRC(vb, 5); AISS(vb, 7);
    VMWAIT(4); APRC(va, 6);
    VMWAIT(0); APRC(vb, 7);
#undef AISS
#undef APRC
}

__device__ __forceinline__ void chunk_gemm(const char* __restrict__ bcol,
                                           const char* As, const int* aoff,
                                           f32x4 acc[4][4]) {
    f16x8 brA[4], brB[4], afA[4], afB[4];
    #pragma unroll
    for (int i = 0; i < 4; ++i)
        #pragma unroll
        for (int j = 0; j < 4; ++j) acc[i][j] = (f32x4){0.f, 0.f, 0.f, 0.f};
    #pragma unroll
    for (int j = 0; j < 4; ++j) brA[j] = *(const f16x8*)(bcol + j * 1024);
    #pragma unroll
    for (int j = 0; j < 4; ++j) brB[j] = *(const f16x8*)(bcol + 32768 + j * 1024);
    #pragma unroll
    for (int i = 0; i < 4; ++i) afA[i] = *(const f16x8*)(As + aoff[i]);
    #pragma unroll
    for (int tt = 0; tt < 8; ++tt) {
        const int t0 = 2 * tt, t1 = t0 + 1;
        #pragma unroll
        for (int i = 0; i < 4; ++i)
            afB[i] = *(const f16x8*)(As + t1 * 4096 + aoff[i]);
        VMWAIT(4);
        #pragma unroll
        for (int i = 0; i < 4; ++i)
            #pragma unroll
            for (int j = 0; j < 4; ++j)
                acc[i][j] = __builtin_amdgcn_mfma_f32_16x16x32_f16(afA[i], brA[j], acc[i][j], 0, 0, 0);
        if (t0 < 14) {
            #pragma unroll
            for (int j = 0; j < 4; ++j)
                brA[j] = *(const f16x8*)(bcol + (t0 + 2) * 32768 + j * 1024);
        }
        if (t1 < 15) {
            #pragma unroll
            for (int i = 0; i < 4; ++i)
                afA[i] = *(const f16x8*)(As + (t1 + 1) * 4096 + aoff[i]);
        }
        if (t1 < 14) { VMWAIT(4); } else { VMWAIT(0); }
        #pragma unroll
        for (int i = 0; i < 4; ++i)
            #pragma unroll
            for (int j = 0; j < 4; ++j)
                acc[i][j] = __builtin_amdgcn_mfma_f32_16x16x32_f16(afB[i], brB[j], acc[i][j], 0, 0, 0);
        if (t1 < 14) {
            #pragma unroll
            for (int j = 0; j < 4; ++j)
                brB[j] = *(const f16x8*)(bcol + (t1 + 2) * 32768 + j * 1024);
        }
    }
}

__global__ __launch_bounds__(256, 2)
void h2_gemm_kernel(const float* __restrict__ hidden,
                    const char* __restrict__ w2img,
                    const float* __restrict__ b2,
                    float* __restrict__ h2o) {
    __shared__ char As[65536];
    const int tid = threadIdx.x, bm = blockIdx.x;
    const int lane = tid & 63, wid = tid >> 6;
    const int lane16 = lane & 15, g = lane >> 4;
    stage_a64(hidden + (size_t)bm * 32768, As, tid);
    __syncthreads();
    int aoff[4];
    #pragma unroll
    for (int i = 0; i < 4; ++i)
        aoff[i] = (i * 16 + lane16) * 64 + ((g ^ ((lane16 >> 1) & 3)) << 4);
    #pragma unroll
    for (int c = 0; c < 2; ++c) {
        const char* bcol = w2img + (size_t)(wid * 128 + c * 64 + lane16) * 64 + g * 16;
        f32x4 acc[4][4];
        chunk_gemm(bcol, As, aoff, acc);
        #pragma unroll
        for (int j = 0; j < 4; ++j) {
            int col = wid * 128 + c * 64 + j * 16 + lane16;
            float bb = b2[col];
            #pragma unroll
            for (int i = 0; i < 4; ++i)
                #pragma unroll
                for (int r = 0; r < 4; ++r)
                    h2o[(size_t)(bm * 64 + i * 16 + g * 4 + r) * 512 + col] = acc[i][j][r] + bb;
        }
    }
}

// ---------------------------------------------------------------------------
// Fused kernel: 512 blocks x 4 batches, 256 thr (4 waves), 2 blocks/CU.
// LDS As [t][row^(t&1)][32k fp16, XOR-swz] 64 KB, single-buffered;
// next batch's A issued 1 float4/thread/step DURING the k-loop (rides the
// vmcnt FIFO behind B), cvt'd to a reg pool, ds-written at batch end.
// Raw s_barrier only -> HBM loads live across softmax/context/write phases.
// ---------------------------------------------------------------------------
__global__ __launch_bounds__(256, 2)
void fused_all_kernel(const float* __restrict__ feat,
                      const char* __restrict__ w1img,
                      const float* __restrict__ h2,
                      const float* __restrict__ b1,
                      const float* __restrict__ wv,
                      float* __restrict__ out) {
    __shared__ char As[65536];
    __shared__ float hhs[512];
    __shared__ float wvs[512];
    __shared__ float spl[256];
    __shared__ float wsm[64];

    const int tid = threadIdx.x;
    const int lane = tid & 63, wid = tid >> 6;
    const int lane16 = lane & 15, g = lane >> 4;
    const int b0 = blockIdx.x * 4;

    // ---- prologue: constants, stage A(b0), prime B regs ----
    {
        float2 wv2 = *(const float2*)(wv + tid * 2);
        float2 b12 = *(const float2*)(b1 + tid * 2);
        float2 h22 = *(const float2*)(h2 + (size_t)b0 * 512 + tid * 2);
        wvs[tid * 2] = wv2.x;  wvs[tid * 2 + 1] = wv2.y;
        hhs[tid * 2] = b12.x + h22.x;  hhs[tid * 2 + 1] = b12.y + h22.y;
    }
    const char* aBase = (const char*)feat + (size_t)wid * 32768 + lane * 16;
    {
        const char* a0 = aBase + (size_t)b0 * 131072;
        #pragma unroll
        for (int gg = 0; gg < 4; ++gg) {
            float4 v[8];
            #pragma unroll
            for (int p = 0; p < 8; ++p)
                v[p] = *(const float4*)(a0 + (gg * 8 + p) * 1024);
            #pragma unroll
            for (int p = 0; p < 8; ++p) {
                const int pi = gg * 8 + p;
                const int row = wid * 16 + (pi >> 1);
                const int t = (pi & 1) * 8 + (lane >> 3);
                const int gq = (lane & 7) >> 1, inner = (lane & 1) * 8;
                const int byte = t * 4096 + ((row ^ (t & 1)) * 64) +
                                 (((gq ^ ((row >> 1) & 3)) << 4) + inner);
                *(u16x4*)(As + byte) = cvt4(v[p]);
            }
        }
    }
    f16x8 brE[4], brO[4];
    {   // B(0), B(1): t=0,1, chunk 0
        const char* bp0 = w1img + (size_t)(wid * 128 + lane16) * 64 + g * 16;
        #pragma unroll
        for (int j = 0; j < 4; ++j) brE[j] = *(const f16x8*)(bp0 + j * 1024);
        FENCE();
        #pragma unroll
        for (int j = 0; j < 4; ++j) brO[j] = *(const f16x8*)(bp0 + 32768 + j * 1024);
        FENCE();
    }
    LGKM0();
    RBAR();

    // ---- batch loop ----
    #pragma unroll 1
    for (int it = 0; it < 4; ++it) {
        const int bcur = b0 + it;
        const int bnext = b0 + (it < 3 ? it + 1 : 3);
        const char* aNext = aBase + (size_t)bnext * 131072;

        u16x4 pool[32];
        float4 win[3];
        f32x4 acc[4][4];
        float sacc[16];
        #pragma unroll
        for (int x = 0; x < 16; ++x) sacc[x] = 0.f;
        #pragma unroll
        for (int i = 0; i < 4; ++i)
            #pragma unroll
            for (int j = 0; j < 4; ++j) acc[i][j] = (f32x4){0.f, 0.f, 0.f, 0.f};

        #pragma unroll
        for (int s = 0; s < 32; ++s) {
            const int c = s >> 4, t = s & 15;
            // cvt A(s-3) (forced landed transitively by this step's B wait)
            if (s >= 3) pool[s - 3] = cvt4(win[(s - 3) % 3]);
            // A-frags for k-tile t
            f16x8 af[4];
            #pragma unroll
            for (int i = 0; i < 4; ++i) {
                const int row = i * 16 + lane16;
                af[i] = *(const f16x8*)(As + t * 4096 + ((row ^ (t & 1)) * 64) +
                                        ((g ^ ((row >> 1) & 3)) << 4));
            }
            // MFMA with current B regs; then refill that buffer with B(s+2)
            const int sn = (s + 2) & 31;
            const int cn = sn >> 4, tn = sn & 15;
            const char* bpn = w1img + (size_t)tn * 32768 +
                              (size_t)(wid * 128 + cn * 64 + lane16) * 64 + g * 16;
            if ((s & 1) == 0) {
                #pragma unroll
                for (int i = 0; i < 4; ++i)
                    #pragma unroll
                    for (int j = 0; j < 4; ++j)
                        acc[i][j] = __builtin_amdgcn_mfma_f32_16x16x32_f16(af[i], brE[j], acc[i][j], 0, 0, 0);
                FENCE();
                #pragma unroll
                for (int j = 0; j < 4; ++j) brE[j] = *(const f16x8*)(bpn + j * 1024);
            } else {
                #pragma unroll
                for (int i = 0; i < 4; ++i)
                    #pragma unroll
                    for (int j = 0; j < 4; ++j)
                        acc[i][j] = __builtin_amdgcn_mfma_f32_16x16x32_f16(af[i], brO[j], acc[i][j], 0, 0, 0);
                FENCE();
                #pragma unroll
                for (int j = 0; j < 4; ++j) brO[j] = *(const f16x8*)(bpn + j * 1024);
            }
            FENCE();
            // A piece for next batch (rides FIFO behind B)
            win[s % 3] = *(const float4*)(aNext + s * 1024);
            FENCE();
            // chunk end: fold acc into scores
            if (t == 15) {
                #pragma unroll
                for (int i = 0; i < 4; ++i)
                    #pragma unroll
                    for (int r = 0; r < 4; ++r) {
                        float sv = 0.f;
                        #pragma unroll
                        for (int j = 0; j < 4; ++j) {
                            const int col = wid * 128 + c * 64 + j * 16 + lane16;
                            float h = acc[i][j][r] + hhs[col];
                            float ex = __expf(2.f * h);
                            sv += (1.f - 2.f * __builtin_amdgcn_rcpf(ex + 1.f)) * wvs[col];
                        }
                        sacc[i * 4 + r] += sv;
                    }
                if (c == 0) {
                    #pragma unroll
                    for (int i = 0; i < 4; ++i)
                        #pragma unroll
                        for (int j = 0; j < 4; ++j) acc[i][j] = (f32x4){0.f, 0.f, 0.f, 0.f};
                }
            }
        }
        // final cvts (drains A(29..31); B(0),B(1) landed by now)
        pool[29] = cvt4(win[29 % 3]);
        pool[30] = cvt4(win[30 % 3]);
        pool[31] = cvt4(win[31 % 3]);
        // h2/b1 for next batch (FIFO otherwise empty here)
        float2 h22 = *(const float2*)(h2 + (size_t)bnext * 512 + tid * 2);
        float2 b12 = *(const float2*)(b1 + tid * 2);
        FENCE();

        // score write + softmax
        #pragma unroll
        for (int i = 0; i < 4; ++i)
            #pragma unroll
            for (int r = 0; r < 4; ++r) {
                float s = sacc[i * 4 + r];
                s += __shfl_xor(s, 1); s += __shfl_xor(s, 2);
                s += __shfl_xor(s, 4); s += __shfl_xor(s, 8);
                if (lane16 == 0) spl[(i * 16 + g * 4 + r) * 4 + wid] = s;
            }
        LGKM0();
        RBAR();
        if (tid < 64) {
            float s = (spl[tid * 4 + 0] + spl[tid * 4 + 1]) +
                      (spl[tid * 4 + 2] + spl[tid * 4 + 3]);
            float m = s;
            #pragma unroll
            for (int off = 32; off; off >>= 1) m = fmaxf(m, __shfl_xor(m, off));
            float e = __expf(s - m);
            float sum = e;
            #pragma unroll
            for (int off = 32; off; off >>= 1) sum += __shfl_xor(sum, off);
            wsm[tid] = e / sum;
        }
        LGKM0();
        RBAR();
        // context from LDS fp16 A; thread owns cols {2tid, 2tid+1}
        {
            const int tpl = tid >> 4;
            const int cin = (tid & 15) * 4;
            float ax = 0.f, ay = 0.f;
            #pragma unroll 8
            for (int sr = 0; sr < 64; ++sr) {
                const int byte = tpl * 4096 + ((sr ^ (tpl & 1)) * 64) +
                                 ((((cin >> 4) ^ ((sr >> 1) & 3)) << 4) | (cin & 15));
                unsigned vv = *(const unsigned*)(As + byte);
                float w = wsm[sr];
                ax += w * (float)__builtin_bit_cast(_Float16, (unsigned short)(vv & 0xffffu));
                ay += w * (float)__builtin_bit_cast(_Float16, (unsigned short)(vv >> 16));
            }
            ((float2*)out)[(size_t)bcur * 256 + tid] = make_float2(ax, ay);
        }
        FENCE();
        RBAR();   // all As reads done -> safe to overwrite
        // write phase: hhs for bnext, pool -> As
        hhs[tid * 2]     = b12.x + h22.x;
        hhs[tid * 2 + 1] = b12.y + h22.y;
        #pragma unroll
        for (int p = 0; p < 32; ++p) {
            const int row = wid * 16 + (p >> 1);
            const int t = (p & 1) * 8 + (lane >> 3);
            const int gq = (lane & 7) >> 1, inner = (lane & 1) * 8;
            const int byte = t * 4096 + ((row ^ (t & 1)) * 64) +
                             (((gq ^ ((row >> 1) & 3)) << 4) + inner);
            *(u16x4*)(As + byte) = pool[p];
        }
        LGKM0();
        RBAR();
    }
}

// ---------------------------------------------------------------------------
extern "C" void kernel_launch(void* const* d_in, const int* in_sizes, int n_in,
                              void* d_out, int out_size, void* d_ws, size_t ws_size,
                              hipStream_t stream) {
    (void)in_sizes; (void)n_in; (void)out_size; (void)ws_size;
    const float* feat   = (const float*)d_in[0];   // [2048,64,512]
    const float* hidden = (const float*)d_in[1];   // [2048,512]
    const float* W1     = (const float*)d_in[2];   // [512,512]
    const float* b1     = (const float*)d_in[3];   // [512]
    const float* W2     = (const float*)d_in[4];   // [512,512]
    const float* b2     = (const float*)d_in[5];   // [512]
    const float* Wv     = (const float*)d_in[6];   // [512,1]
    // d_in[7] = bv: softmax shift-invariant, unused.
    float* out = (float*)d_out;                    // [2048,512]

    char* ws = (char*)d_ws;
    unsigned short* w1img = (unsigned short*)(ws);            // 512 KB
    unsigned short* w2img = (unsigned short*)(ws + 524288);   // 512 KB
    float* h2 = (float*)(ws + 1048576);                       // 4 MB

    convert_w_kernel<<<dim3(512, 2), dim3(256), 0, stream>>>(W1, W2, w1img, w2img);
    h2_gemm_kernel<<<dim3(32), dim3(256), 0, stream>>>(hidden, (const char*)w2img, b2, h2);
    fused_all_kernel<<<dim3(512), dim3(256), 0, stream>>>(feat, (const char*)w1img, h2, b1, Wv, out);
}